// Round 1
// baseline (3229.194 us; speedup 1.0000x reference)
//
#include <hip/hip_runtime.h>
#include <cstdint>
#include <cstddef>

#define EPG 160
#define HC  3072
#define DD  1024

__device__ __forceinline__ unsigned fenc(float f){
  unsigned u = __float_as_uint(f);
  return (u & 0x80000000u) ? ~u : (u | 0x80000000u);
}
__device__ __forceinline__ float fdec(unsigned u){
  return (u & 0x80000000u) ? __uint_as_float(u ^ 0x80000000u) : __uint_as_float(~u);
}

// ---------------- SGEMM: C[M,N] = A[M,K] @ B[K,N] (+bias) (+relu) ----------------
// M % 128 == 0, N % 128 == 0 guaranteed by launches; K arbitrary.
__global__ __launch_bounds__(256) void sgemm_kernel(
    const float* __restrict__ A, const float* __restrict__ B,
    const float* __restrict__ bias, float* __restrict__ C,
    int M, int N, int K, int relu)
{
  __shared__ float As[16][132];
  __shared__ float Bs[16][132];
  const int tid  = threadIdx.x;
  const int brow = blockIdx.y * 128;
  const int bcol = blockIdx.x * 128;
  const int trow = (tid >> 4) * 8;
  const int tcol = (tid & 15) * 8;
  const int ar = tid >> 2, ac = (tid & 3) * 4;
  const int br = tid >> 5, bc = (tid & 31) * 4;
  float acc[8][8];
  #pragma unroll
  for (int i = 0; i < 8; i++)
    #pragma unroll
    for (int j = 0; j < 8; j++) acc[i][j] = 0.f;
  const bool k16 = (K & 15) == 0;
  for (int k0 = 0; k0 < K; k0 += 16) {
    if (k16) {
      #pragma unroll
      for (int i = 0; i < 2; i++) {
        int r = ar + i * 64;
        const float4 v = *(const float4*)&A[(size_t)(brow + r) * K + k0 + ac];
        As[ac + 0][r] = v.x; As[ac + 1][r] = v.y; As[ac + 2][r] = v.z; As[ac + 3][r] = v.w;
      }
      #pragma unroll
      for (int i = 0; i < 2; i++) {
        int r = br + i * 8;
        *(float4*)&Bs[r][bc] = *(const float4*)&B[(size_t)(k0 + r) * N + bcol + bc];
      }
    } else {
      #pragma unroll
      for (int i = 0; i < 2; i++) {
        int r = ar + i * 64;
        #pragma unroll
        for (int q = 0; q < 4; q++) {
          int kc = k0 + ac + q;
          As[ac + q][r] = (kc < K) ? A[(size_t)(brow + r) * K + kc] : 0.f;
        }
      }
      #pragma unroll
      for (int i = 0; i < 2; i++) {
        int r = br + i * 8;
        float4 v = make_float4(0.f, 0.f, 0.f, 0.f);
        if (k0 + r < K) v = *(const float4*)&B[(size_t)(k0 + r) * N + bcol + bc];
        *(float4*)&Bs[r][bc] = v;
      }
    }
    __syncthreads();
    #pragma unroll
    for (int kk = 0; kk < 16; kk++) {
      float a[8], b[8];
      *(float4*)&a[0] = *(const float4*)&As[kk][trow];
      *(float4*)&a[4] = *(const float4*)&As[kk][trow + 4];
      *(float4*)&b[0] = *(const float4*)&Bs[kk][tcol];
      *(float4*)&b[4] = *(const float4*)&Bs[kk][tcol + 4];
      #pragma unroll
      for (int i = 0; i < 8; i++)
        #pragma unroll
        for (int j = 0; j < 8; j++) acc[i][j] += a[i] * b[j];
    }
    __syncthreads();
  }
  #pragma unroll
  for (int i = 0; i < 8; i++) {
    const size_t row = (size_t)(brow + trow + i) * N + bcol + tcol;
    #pragma unroll
    for (int j0 = 0; j0 < 8; j0 += 4) {
      float4 v;
      float* pv = &v.x;
      #pragma unroll
      for (int q = 0; q < 4; q++) {
        float t = acc[i][j0 + q];
        if (bias) t += bias[bcol + tcol + j0 + q];
        if (relu) t = t > 0.f ? t : 0.f;
        pv[q] = t;
      }
      *(float4*)&C[row + j0] = v;
    }
  }
}

// ---------------- per-(node,head) attention dot products ----------------
// als[n*3+h] = sum_c xl[n, h*1024+c] * a_src[h*1024+c]; same for ald.
__global__ __launch_bounds__(256) void al_kernel(
    const float* __restrict__ xl, const float* __restrict__ a_s, const float* __restrict__ a_d,
    float* __restrict__ als, float* __restrict__ ald, int N)
{
  int w = (blockIdx.x * 256 + threadIdx.x) >> 6;
  int lane = threadIdx.x & 63;
  if (w >= N * 3) return;
  int h = w % 3;
  const float* row = xl + (size_t)(w / 3) * HC + h * DD;
  const float* vs = a_s + h * DD;
  const float* vd = a_d + h * DD;
  float ps = 0.f, pd = 0.f;
  #pragma unroll 4
  for (int i = lane; i < DD; i += 64) { float v = row[i]; ps += v * vs[i]; pd += v * vd[i]; }
  #pragma unroll
  for (int off = 32; off; off >>= 1) { ps += __shfl_down(ps, off); pd += __shfl_down(pd, off); }
  if (lane == 0) { als[w] = ps; ald[w] = pd; }
}

// ---------------- ||p_i|| for the three pools ----------------
__global__ __launch_bounds__(256) void norm_kernel(
    const float* __restrict__ p1, const float* __restrict__ p2,
    const float* __restrict__ p3, float* __restrict__ nrm)
{
  const float* p = blockIdx.x == 0 ? p1 : (blockIdx.x == 1 ? p2 : p3);
  __shared__ float red[4];
  int tid = threadIdx.x;
  float s = 0.f;
  for (int i = tid; i < DD; i += 256) { float v = p[i]; s += v * v; }
  #pragma unroll
  for (int off = 32; off; off >>= 1) s += __shfl_down(s, off);
  if ((tid & 63) == 0) red[tid >> 6] = s;
  __syncthreads();
  if (tid == 0) nrm[blockIdx.x] = sqrtf(red[0] + red[1] + red[2] + red[3]);
}

// ---------------- scores: tanh((h . p) / ||p||) ----------------
__global__ __launch_bounds__(256) void score_kernel(
    const float* __restrict__ hbuf, const float* __restrict__ p,
    const float* __restrict__ nrm, int stage, float* __restrict__ sc, int N)
{
  int w = (blockIdx.x * 256 + threadIdx.x) >> 6;
  int lane = threadIdx.x & 63;
  if (w >= N) return;
  const float* row = hbuf + (size_t)w * DD;
  float s = 0.f;
  #pragma unroll 4
  for (int i = lane; i < DD; i += 64) s += row[i] * p[i];
  #pragma unroll
  for (int off = 32; off; off >>= 1) s += __shfl_down(s, off);
  if (lane == 0) sc[w] = tanhf(s / nrm[stage]);
}

// ---------------- fused GAT attention + aggregation ----------------
// grid = (256 graphs, 3 heads). One block handles one graph, one head (1024 cols).
// Self-loops are implicit (one per node). emask == nullptr means all edges valid.
__global__ __launch_bounds__(256) void gat_agg(
    const float* __restrict__ xl, const float* __restrict__ als, const float* __restrict__ ald,
    const int* __restrict__ esrc, const int* __restrict__ edst, const int* __restrict__ emask,
    const float* __restrict__ gbias, float* __restrict__ out, int npg)
{
  const int g = blockIdx.x;
  const int h = blockIdx.y;
  const int tid = threadIdx.x;
  const int base = g * npg;
  __shared__ float s_as[32], s_ad[32], s_mx[32], s_den[32], s_self[32];
  __shared__ unsigned s_mxu[32];
  __shared__ float s_alpha[EPG];
  __shared__ int s_srcl[EPG];
  __shared__ int s_start[33];
  __shared__ int s_cnt[32], s_cur[32];
  __shared__ int s_list[EPG];

  if (tid < npg) {
    s_as[tid] = als[(size_t)(base + tid) * 3 + h];
    s_ad[tid] = ald[(size_t)(base + tid) * 3 + h];
    s_mxu[tid] = 0u;
    s_den[tid] = 0.f;
    s_cnt[tid] = 0;
    s_cur[tid] = 0;
  }
  __syncthreads();

  int ok = 0, dl = 0;
  float lg = 0.f;
  if (tid < EPG) {
    int ei = g * EPG + tid;
    ok = emask ? emask[ei] : 1;
    if (ok) {
      int sl = esrc[ei] - base;
      dl = edst[ei] - base;
      s_srcl[tid] = sl;
      float v = s_as[sl] + s_ad[dl];
      lg = v > 0.f ? v : 0.2f * v;          // leaky_relu 0.2
      atomicMax(&s_mxu[dl], fenc(lg));
      atomicAdd(&s_cnt[dl], 1);
    }
  }
  float slg = 0.f;
  if (tid < npg) {
    float v = s_as[tid] + s_ad[tid];
    slg = v > 0.f ? v : 0.2f * v;
    atomicMax(&s_mxu[tid], fenc(slg));
  }
  __syncthreads();

  if (tid < npg) s_mx[tid] = fdec(s_mxu[tid]);
  if (tid == 0) {
    int run = 0;
    for (int n = 0; n < npg; n++) { s_start[n] = run; run += s_cnt[n]; }
    s_start[npg] = run;
  }
  __syncthreads();

  float ex = 0.f;
  if (tid < EPG && ok) {
    ex = expf(lg - s_mx[dl]);
    atomicAdd(&s_den[dl], ex);
    int p = s_start[dl] + atomicAdd(&s_cur[dl], 1);
    s_list[p] = tid;
  }
  if (tid < npg) {
    float e2 = expf(slg - s_mx[tid]);
    s_self[tid] = e2;
    atomicAdd(&s_den[tid], e2);
  }
  __syncthreads();

  if (tid < EPG && ok) s_alpha[tid] = ex / s_den[dl];
  if (tid < npg) s_self[tid] = s_self[tid] / s_den[tid];
  __syncthreads();

  // aggregation: each thread owns one float4 of this head's 1024 columns
  const int c = h * DD + tid * 4;
  const float4 b4 = *(const float4*)&gbias[c];
  for (int n = 0; n < npg; n++) {
    const size_t rowo = (size_t)(base + n) * HC + c;
    const float4 v = *(const float4*)&xl[rowo];
    float a0 = s_self[n];
    float4 acc;
    acc.x = a0 * v.x; acc.y = a0 * v.y; acc.z = a0 * v.z; acc.w = a0 * v.w;
    const int st = s_start[n], en = s_start[n + 1];
    for (int q = st; q < en; q++) {
      int e = s_list[q];
      float a = s_alpha[e];
      const float4 u = *(const float4*)&xl[(size_t)(base + s_srcl[e]) * HC + c];
      acc.x += a * u.x; acc.y += a * u.y; acc.z += a * u.z; acc.w += a * u.w;
    }
    acc.x += b4.x; acc.y += b4.y; acc.z += b4.z; acc.w += b4.w;
    *(float4*)&out[rowo] = acc;
  }
}

// ---------------- TopK pool: stable top-k (score desc, index asc), gate, gap mean, edge remap ----
__global__ __launch_bounds__(256) void pool_kernel(
    const float* __restrict__ hbuf, const float* __restrict__ sc,
    const int* __restrict__ cs, const int* __restrict__ cd, const int* __restrict__ cm,
    int npg, int k,
    float* __restrict__ xnew, float* __restrict__ gap,
    int* __restrict__ ns, int* __restrict__ nd, int* __restrict__ nm)
{
  int g = blockIdx.x, tid = threadIdx.x;
  __shared__ float ssc[32];
  __shared__ int sord[32];
  __shared__ int snp[32];
  if (tid < npg) ssc[tid] = sc[g * npg + tid];
  __syncthreads();
  if (tid == 0) {
    for (int i = 0; i < npg; i++) sord[i] = i;
    for (int i = 1; i < npg; i++) {          // stable insertion sort, descending
      int oi = sord[i]; float v = ssc[oi]; int j = i - 1;
      while (j >= 0 && ssc[sord[j]] < v) { sord[j + 1] = sord[j]; j--; }
      sord[j + 1] = oi;
    }
  }
  __syncthreads();
  if (tid < npg) snp[tid] = -1;
  __syncthreads();
  if (tid < k) snp[sord[tid]] = tid;
  __syncthreads();

  float acc0 = 0.f, acc1 = 0.f, acc2 = 0.f, acc3 = 0.f;
  for (int r = 0; r < k; r++) {
    int ol = sord[r];
    float s = ssc[ol];
    const float* hr = hbuf + (size_t)(g * npg + ol) * DD;
    float* xr = xnew + (size_t)(g * k + r) * DD;
    float v0 = hr[tid] * s, v1 = hr[tid + 256] * s, v2 = hr[tid + 512] * s, v3 = hr[tid + 768] * s;
    xr[tid] = v0; xr[tid + 256] = v1; xr[tid + 512] = v2; xr[tid + 768] = v3;
    acc0 += v0; acc1 += v1; acc2 += v2; acc3 += v3;
  }
  float fk = (float)k;
  gap[(size_t)g * DD + tid]       = acc0 / fk;
  gap[(size_t)g * DD + tid + 256] = acc1 / fk;
  gap[(size_t)g * DD + tid + 512] = acc2 / fk;
  gap[(size_t)g * DD + tid + 768] = acc3 / fk;

  for (int e = tid; e < EPG; e += 256) {
    int ei = g * EPG + e;
    int ok = cm ? cm[ei] : 1;
    int m2 = 0, a = 0, b2 = 0;
    if (ok) {
      int sl = cs[ei] - g * npg, dl = cd[ei] - g * npg;
      int nsl = snp[sl], ndl = snp[dl];
      if (nsl >= 0 && ndl >= 0) { m2 = 1; a = g * k + nsl; b2 = g * k + ndl; }
    }
    ns[ei] = a; nd[ei] = b2; nm[ei] = m2;
  }
}

// ---------------- z = x1 + x2 + x3 ----------------
__global__ __launch_bounds__(256) void zadd_kernel(
    const float* __restrict__ a, const float* __restrict__ b,
    const float* __restrict__ c, float* __restrict__ o)
{
  int i = blockIdx.x * 256 + threadIdx.x;
  o[i] = a[i] + b[i] + c[i];
}

// ---------------- final linear to scalar ----------------
__global__ __launch_bounds__(256) void l2_kernel(
    const float* __restrict__ z2, const float* __restrict__ w,
    const float* __restrict__ b, float* __restrict__ out)
{
  int row = (blockIdx.x * 256 + threadIdx.x) >> 6;
  int lane = threadIdx.x & 63;
  if (row >= 256) return;
  const float* r = z2 + (size_t)row * DD;
  float s = 0.f;
  #pragma unroll 4
  for (int i = lane; i < DD; i += 64) s += r[i] * w[i];
  #pragma unroll
  for (int off = 32; off; off >>= 1) s += __shfl_down(s, off);
  if (lane == 0) out[row] = s + b[0];
}

extern "C" void kernel_launch(void* const* d_in, const int* in_sizes, int n_in,
                              void* d_out, int out_size, void* d_ws, size_t ws_size,
                              hipStream_t stream)
{
  (void)in_sizes; (void)n_in; (void)out_size; (void)ws_size;
  const float* x    = (const float*)d_in[0];
  const int*   eidx = (const int*)d_in[2];
  const float* g1W = (const float*)d_in[4];
  const float* g1as= (const float*)d_in[5];
  const float* g1ad= (const float*)d_in[6];
  const float* g1b = (const float*)d_in[7];
  const float* t1W = (const float*)d_in[8];
  const float* t1b = (const float*)d_in[9];
  const float* p1  = (const float*)d_in[10];
  const float* g2W = (const float*)d_in[11];
  const float* g2as= (const float*)d_in[12];
  const float* g2ad= (const float*)d_in[13];
  const float* g2b = (const float*)d_in[14];
  const float* t2W = (const float*)d_in[15];
  const float* t2b = (const float*)d_in[16];
  const float* p2  = (const float*)d_in[17];
  const float* g3W = (const float*)d_in[18];
  const float* g3as= (const float*)d_in[19];
  const float* g3ad= (const float*)d_in[20];
  const float* g3b = (const float*)d_in[21];
  const float* t3W = (const float*)d_in[22];
  const float* t3b = (const float*)d_in[23];
  const float* p3  = (const float*)d_in[24];
  const float* l1W = (const float*)d_in[25];
  const float* l1b = (const float*)d_in[26];
  const float* l2W = (const float*)d_in[27];
  const float* l2b = (const float*)d_in[28];
  float* outp = (float*)d_out;

  float* W = (float*)d_ws;
  size_t o = 0;
  float* bufA = W + o; o += (size_t)8192 * HC;   // 25.17M floats
  float* bufB = W + o; o += (size_t)8192 * HC;
  float* ALS = W + o; o += 8192 * 3;
  float* ALD = W + o; o += 8192 * 3;
  float* SC  = W + o; o += 8192;
  float* NRM = W + o; o += 4;
  float* X1  = W + o; o += 256 * DD;
  float* X2  = W + o; o += 256 * DD;
  float* X3  = W + o; o += 256 * DD;
  float* ZB  = W + o; o += 256 * DD;
  float* Z2  = W + o; o += 256 * DD;
  int* E0s = (int*)(W + o); o += 40960;
  int* E0d = (int*)(W + o); o += 40960;
  int* E0m = (int*)(W + o); o += 40960;
  int* E1s = (int*)(W + o); o += 40960;
  int* E1d = (int*)(W + o); o += 40960;
  int* E1m = (int*)(W + o); o += 40960;

  const int* es1 = eidx;           // src row of edge_index [2, 40960]
  const int* ed1 = eidx + 40960;   // dst row

  norm_kernel<<<3, 256, 0, stream>>>(p1, p2, p3, NRM);

  // -------- stage 1: N=8192, npg=32 -> k=26 --------
  sgemm_kernel<<<dim3(24, 64), 256, 0, stream>>>(x, g1W, nullptr, bufA, 8192, HC, 30, 0);
  al_kernel<<<6144, 256, 0, stream>>>(bufA, g1as, g1ad, ALS, ALD, 8192);
  gat_agg<<<dim3(256, 3), 256, 0, stream>>>(bufA, ALS, ALD, es1, ed1, nullptr, g1b, bufB, 32);
  sgemm_kernel<<<dim3(8, 64), 256, 0, stream>>>(bufB, t1W, t1b, bufA, 8192, DD, HC, 0);
  score_kernel<<<2048, 256, 0, stream>>>(bufA, p1, NRM, 0, SC, 8192);
  pool_kernel<<<256, 256, 0, stream>>>(bufA, SC, es1, ed1, nullptr, 32, 26, bufB, X1, E0s, E0d, E0m);

  // -------- stage 2: N=6656, npg=26 -> k=13 --------
  sgemm_kernel<<<dim3(24, 52), 256, 0, stream>>>(bufB, g2W, nullptr, bufA, 6656, HC, DD, 0);
  al_kernel<<<4992, 256, 0, stream>>>(bufA, g2as, g2ad, ALS, ALD, 6656);
  gat_agg<<<dim3(256, 3), 256, 0, stream>>>(bufA, ALS, ALD, E0s, E0d, E0m, g2b, bufB, 26);
  sgemm_kernel<<<dim3(8, 52), 256, 0, stream>>>(bufB, t2W, t2b, bufA, 6656, DD, HC, 0);
  score_kernel<<<1664, 256, 0, stream>>>(bufA, p2, NRM, 1, SC, 6656);
  pool_kernel<<<256, 256, 0, stream>>>(bufA, SC, E0s, E0d, E0m, 26, 13, bufB, X2, E1s, E1d, E1m);

  // -------- stage 3: N=3328, npg=13 -> k=4 --------
  sgemm_kernel<<<dim3(24, 26), 256, 0, stream>>>(bufB, g3W, nullptr, bufA, 3328, HC, DD, 0);
  al_kernel<<<2496, 256, 0, stream>>>(bufA, g3as, g3ad, ALS, ALD, 3328);
  gat_agg<<<dim3(256, 3), 256, 0, stream>>>(bufA, ALS, ALD, E1s, E1d, E1m, g3b, bufB, 13);
  sgemm_kernel<<<dim3(8, 26), 256, 0, stream>>>(bufB, t3W, t3b, bufA, 3328, DD, HC, 0);
  score_kernel<<<832, 256, 0, stream>>>(bufA, p3, NRM, 2, SC, 3328);
  pool_kernel<<<256, 256, 0, stream>>>(bufA, SC, E1s, E1d, E1m, 13, 4, bufB, X3, E0s, E0d, E0m);

  // -------- head --------
  zadd_kernel<<<1024, 256, 0, stream>>>(X1, X2, X3, ZB);
  sgemm_kernel<<<dim3(8, 2), 256, 0, stream>>>(ZB, l1W, l1b, Z2, 256, DD, DD, 1);
  l2_kernel<<<64, 256, 0, stream>>>(Z2, l2W, l2b, outp);
}

// Round 2
// 1225.277 us; speedup vs baseline: 2.6355x; 2.6355x over previous
//
#include <hip/hip_runtime.h>
#include <cstdint>
#include <cstddef>

#define EPG 160
#define HC  3072
#define DD  1024
#define LDP 40   // LDS row pitch in halfs (32 k-halfs + 8 pad = 80B rows)

typedef _Float16 f16x8 __attribute__((ext_vector_type(8)));
typedef float    f32x4 __attribute__((ext_vector_type(4)));

__device__ __forceinline__ unsigned fenc(float f){
  unsigned u = __float_as_uint(f);
  return (u & 0x80000000u) ? ~u : (u | 0x80000000u);
}
__device__ __forceinline__ float fdec(unsigned u){
  return (u & 0x80000000u) ? __uint_as_float(u ^ 0x80000000u) : __uint_as_float(~u);
}

// ---------------- weight transpose + fp16 split: W[K][N] -> WTh/WTl[N][Kpad] ----------------
__global__ __launch_bounds__(256) void wtrans_kernel(
    const float* __restrict__ W, _Float16* __restrict__ WTh, _Float16* __restrict__ WTl,
    int K, int N, int Kpad)
{
  __shared__ float t[32][33];
  const int tx = threadIdx.x, ty = threadIdx.y;
  const int n0 = blockIdx.x * 32, k0 = blockIdx.y * 32;
  #pragma unroll
  for (int i = 0; i < 4; i++) {
    int k = k0 + ty + i * 8;
    t[ty + i * 8][tx] = (k < K) ? W[(size_t)k * N + n0 + tx] : 0.f;
  }
  __syncthreads();
  #pragma unroll
  for (int i = 0; i < 4; i++) {
    int n = n0 + ty + i * 8;
    float v = t[tx][ty + i * 8];
    _Float16 h = (_Float16)v;
    float r = v - (float)h;
    WTh[(size_t)n * Kpad + k0 + tx] = h;
    WTl[(size_t)n * Kpad + k0 + tx] = (_Float16)r;
  }
}

// ---------------- split-fp16 MFMA GEMM: C[M,N] = A[M,K] @ B[K,N] (+bias) ----------------
// A fp32 row-major (split to fp16 h/l in staging registers).
// B pre-transposed+split: BTh/BTl are [N][Kpw] fp16, Kpw = 32-aligned K.
// M%128==0, N%128==0. 256 threads, 128x128 tile, BK=32, 4 waves in 2x2, 4x4 frags/wave.
__global__ __launch_bounds__(256) void mfma_gemm(
    const float* __restrict__ A, const _Float16* __restrict__ BTh, const _Float16* __restrict__ BTl,
    const float* __restrict__ bias, float* __restrict__ C,
    int M, int N, int K, int Kpw)
{
  __shared__ _Float16 sAh[128 * LDP];
  __shared__ _Float16 sAl[128 * LDP];
  __shared__ _Float16 sBh[128 * LDP];
  __shared__ _Float16 sBl[128 * LDP];

  const int tid  = threadIdx.x;
  const int brow = blockIdx.y * 128;
  const int bcol = blockIdx.x * 128;
  const int srow = tid >> 1;          // staging row/col 0..127
  const int skh  = (tid & 1) * 16;    // staging k-offset in halfs: 0 or 16
  const int lane = tid & 63;
  const int wid  = tid >> 6;
  const int wr = (wid >> 1) * 64;     // wave row base
  const int wc = (wid & 1) * 64;      // wave col base
  const int fr = lane & 15;
  const int ks = (lane >> 4) * 8;     // fragment k-offset in halfs

  f32x4 acc[4][4];
  #pragma unroll
  for (int m = 0; m < 4; m++)
    #pragma unroll
    for (int n = 0; n < 4; n++) acc[m][n] = (f32x4)0.0f;

  const bool fast = ((K & 3) == 0);
  const size_t arow = (size_t)(brow + srow) * K;
  const _Float16* bsrc_h = BTh + (size_t)(bcol + srow) * Kpw + skh;
  const _Float16* bsrc_l = BTl + (size_t)(bcol + srow) * Kpw + skh;

  for (int k0 = 0; k0 < K; k0 += 32) {
    // ---- global -> regs ----
    float av[16];
    if (fast && (k0 + 32 <= K)) {
      #pragma unroll
      for (int q = 0; q < 4; q++)
        *(float4*)&av[q * 4] = *(const float4*)&A[arow + k0 + skh + q * 4];
    } else {
      #pragma unroll
      for (int j = 0; j < 16; j++) {
        int k = k0 + skh + j;
        av[j] = (k < K) ? A[arow + k] : 0.f;
      }
    }
    const f16x8 bvh0 = *(const f16x8*)(bsrc_h + k0);
    const f16x8 bvh1 = *(const f16x8*)(bsrc_h + k0 + 8);
    const f16x8 bvl0 = *(const f16x8*)(bsrc_l + k0);
    const f16x8 bvl1 = *(const f16x8*)(bsrc_l + k0 + 8);

    // ---- fp16 split in registers ----
    f16x8 ah0, ah1, al0, al1;
    #pragma unroll
    for (int j = 0; j < 8; j++) {
      float v  = av[j];
      _Float16 h = (_Float16)v;
      ah0[j] = h; al0[j] = (_Float16)(v - (float)h);
      float v2 = av[j + 8];
      _Float16 h2 = (_Float16)v2;
      ah1[j] = h2; al1[j] = (_Float16)(v2 - (float)h2);
    }

    __syncthreads();   // prior tile fully consumed
    *(f16x8*)&sAh[srow * LDP + skh]     = ah0;
    *(f16x8*)&sAh[srow * LDP + skh + 8] = ah1;
    *(f16x8*)&sAl[srow * LDP + skh]     = al0;
    *(f16x8*)&sAl[srow * LDP + skh + 8] = al1;
    *(f16x8*)&sBh[srow * LDP + skh]     = bvh0;
    *(f16x8*)&sBh[srow * LDP + skh + 8] = bvh1;
    *(f16x8*)&sBl[srow * LDP + skh]     = bvl0;
    *(f16x8*)&sBl[srow * LDP + skh + 8] = bvl1;
    __syncthreads();   // tile visible

    // ---- MFMA: hh + lh + hl ----
    f16x8 bh[4], bl[4];
    #pragma unroll
    for (int n = 0; n < 4; n++) {
      bh[n] = *(const f16x8*)&sBh[(wc + n * 16 + fr) * LDP + ks];
      bl[n] = *(const f16x8*)&sBl[(wc + n * 16 + fr) * LDP + ks];
    }
    #pragma unroll
    for (int m = 0; m < 4; m++) {
      const f16x8 ah = *(const f16x8*)&sAh[(wr + m * 16 + fr) * LDP + ks];
      const f16x8 al = *(const f16x8*)&sAl[(wr + m * 16 + fr) * LDP + ks];
      #pragma unroll
      for (int n = 0; n < 4; n++) {
        acc[m][n] = __builtin_amdgcn_mfma_f32_16x16x32_f16(ah, bh[n], acc[m][n], 0, 0, 0);
        acc[m][n] = __builtin_amdgcn_mfma_f32_16x16x32_f16(al, bh[n], acc[m][n], 0, 0, 0);
        acc[m][n] = __builtin_amdgcn_mfma_f32_16x16x32_f16(ah, bl[n], acc[m][n], 0, 0, 0);
      }
    }
  }

  // ---- epilogue: C/D layout col=lane&15, row=(lane>>4)*4+q (m89-verified) ----
  const int crow0 = brow + wr + (lane >> 4) * 4;
  const int ccol0 = bcol + wc + fr;
  #pragma unroll
  for (int n = 0; n < 4; n++) {
    const int col = ccol0 + n * 16;
    const float bv = bias ? bias[col] : 0.f;
    #pragma unroll
    for (int m = 0; m < 4; m++) {
      const int row = crow0 + m * 16;
      #pragma unroll
      for (int q = 0; q < 4; q++)
        C[(size_t)(row + q) * N + col] = acc[m][n][q] + bv;
    }
  }
}

// ---------------- fp32 SGEMM (kept for the small l1 head GEMM) ----------------
__global__ __launch_bounds__(256) void sgemm_kernel(
    const float* __restrict__ A, const float* __restrict__ B,
    const float* __restrict__ bias, float* __restrict__ C,
    int M, int N, int K, int relu)
{
  __shared__ float As[16][132];
  __shared__ float Bs[16][132];
  const int tid  = threadIdx.x;
  const int brow = blockIdx.y * 128;
  const int bcol = blockIdx.x * 128;
  const int trow = (tid >> 4) * 8;
  const int tcol = (tid & 15) * 8;
  const int ar = tid >> 2, ac = (tid & 3) * 4;
  const int br = tid >> 5, bc = (tid & 31) * 4;
  float acc[8][8];
  #pragma unroll
  for (int i = 0; i < 8; i++)
    #pragma unroll
    for (int j = 0; j < 8; j++) acc[i][j] = 0.f;
  for (int k0 = 0; k0 < K; k0 += 16) {
    #pragma unroll
    for (int i = 0; i < 2; i++) {
      int r = ar + i * 64;
      const float4 v = *(const float4*)&A[(size_t)(brow + r) * K + k0 + ac];
      As[ac + 0][r] = v.x; As[ac + 1][r] = v.y; As[ac + 2][r] = v.z; As[ac + 3][r] = v.w;
    }
    #pragma unroll
    for (int i = 0; i < 2; i++) {
      int r = br + i * 8;
      *(float4*)&Bs[r][bc] = *(const float4*)&B[(size_t)(k0 + r) * N + bcol + bc];
    }
    __syncthreads();
    #pragma unroll
    for (int kk = 0; kk < 16; kk++) {
      float a[8], b[8];
      *(float4*)&a[0] = *(const float4*)&As[kk][trow];
      *(float4*)&a[4] = *(const float4*)&As[kk][trow + 4];
      *(float4*)&b[0] = *(const float4*)&Bs[kk][tcol];
      *(float4*)&b[4] = *(const float4*)&Bs[kk][tcol + 4];
      #pragma unroll
      for (int i = 0; i < 8; i++)
        #pragma unroll
        for (int j = 0; j < 8; j++) acc[i][j] += a[i] * b[j];
    }
    __syncthreads();
  }
  #pragma unroll
  for (int i = 0; i < 8; i++) {
    const size_t row = (size_t)(brow + trow + i) * N + bcol + tcol;
    #pragma unroll
    for (int j0 = 0; j0 < 8; j0 += 4) {
      float4 v;
      float* pv = &v.x;
      #pragma unroll
      for (int q = 0; q < 4; q++) {
        float t = acc[i][j0 + q];
        if (bias) t += bias[bcol + tcol + j0 + q];
        if (relu) t = t > 0.f ? t : 0.f;
        pv[q] = t;
      }
      *(float4*)&C[row + j0] = v;
    }
  }
}

// ---------------- per-(node,head) attention dot products ----------------
__global__ __launch_bounds__(256) void al_kernel(
    const float* __restrict__ xl, const float* __restrict__ a_s, const float* __restrict__ a_d,
    float* __restrict__ als, float* __restrict__ ald, int N)
{
  int w = (blockIdx.x * 256 + threadIdx.x) >> 6;
  int lane = threadIdx.x & 63;
  if (w >= N * 3) return;
  int h = w % 3;
  const float* row = xl + (size_t)(w / 3) * HC + h * DD;
  const float* vs = a_s + h * DD;
  const float* vd = a_d + h * DD;
  float ps = 0.f, pd = 0.f;
  #pragma unroll 4
  for (int i = lane; i < DD; i += 64) { float v = row[i]; ps += v * vs[i]; pd += v * vd[i]; }
  #pragma unroll
  for (int off = 32; off; off >>= 1) { ps += __shfl_down(ps, off); pd += __shfl_down(pd, off); }
  if (lane == 0) { als[w] = ps; ald[w] = pd; }
}

// ---------------- ||p_i|| ----------------
__global__ __launch_bounds__(256) void norm_kernel(
    const float* __restrict__ p1, const float* __restrict__ p2,
    const float* __restrict__ p3, float* __restrict__ nrm)
{
  const float* p = blockIdx.x == 0 ? p1 : (blockIdx.x == 1 ? p2 : p3);
  __shared__ float red[4];
  int tid = threadIdx.x;
  float s = 0.f;
  for (int i = tid; i < DD; i += 256) { float v = p[i]; s += v * v; }
  #pragma unroll
  for (int off = 32; off; off >>= 1) s += __shfl_down(s, off);
  if ((tid & 63) == 0) red[tid >> 6] = s;
  __syncthreads();
  if (tid == 0) nrm[blockIdx.x] = sqrtf(red[0] + red[1] + red[2] + red[3]);
}

// ---------------- scores: tanh((h . p) / ||p||) ----------------
__global__ __launch_bounds__(256) void score_kernel(
    const float* __restrict__ hbuf, const float* __restrict__ p,
    const float* __restrict__ nrm, int stage, float* __restrict__ sc, int N)
{
  int w = (blockIdx.x * 256 + threadIdx.x) >> 6;
  int lane = threadIdx.x & 63;
  if (w >= N) return;
  const float* row = hbuf + (size_t)w * DD;
  float s = 0.f;
  #pragma unroll 4
  for (int i = lane; i < DD; i += 64) s += row[i] * p[i];
  #pragma unroll
  for (int off = 32; off; off >>= 1) s += __shfl_down(s, off);
  if (lane == 0) sc[w] = tanhf(s / nrm[stage]);
}

// ---------------- fused GAT attention + aggregation ----------------
__global__ __launch_bounds__(256) void gat_agg(
    const float* __restrict__ xl, const float* __restrict__ als, const float* __restrict__ ald,
    const int* __restrict__ esrc, const int* __restrict__ edst, const int* __restrict__ emask,
    const float* __restrict__ gbias, float* __restrict__ out, int npg)
{
  const int g = blockIdx.x;
  const int h = blockIdx.y;
  const int tid = threadIdx.x;
  const int base = g * npg;
  __shared__ float s_as[32], s_ad[32], s_mx[32], s_den[32], s_self[32];
  __shared__ unsigned s_mxu[32];
  __shared__ float s_alpha[EPG];
  __shared__ int s_srcl[EPG];
  __shared__ int s_start[33];
  __shared__ int s_cnt[32], s_cur[32];
  __shared__ int s_list[EPG];

  if (tid < npg) {
    s_as[tid] = als[(size_t)(base + tid) * 3 + h];
    s_ad[tid] = ald[(size_t)(base + tid) * 3 + h];
    s_mxu[tid] = 0u;
    s_den[tid] = 0.f;
    s_cnt[tid] = 0;
    s_cur[tid] = 0;
  }
  __syncthreads();

  int ok = 0, dl = 0;
  float lg = 0.f;
  if (tid < EPG) {
    int ei = g * EPG + tid;
    ok = emask ? emask[ei] : 1;
    if (ok) {
      int sl = esrc[ei] - base;
      dl = edst[ei] - base;
      s_srcl[tid] = sl;
      float v = s_as[sl] + s_ad[dl];
      lg = v > 0.f ? v : 0.2f * v;
      atomicMax(&s_mxu[dl], fenc(lg));
      atomicAdd(&s_cnt[dl], 1);
    }
  }
  float slg = 0.f;
  if (tid < npg) {
    float v = s_as[tid] + s_ad[tid];
    slg = v > 0.f ? v : 0.2f * v;
    atomicMax(&s_mxu[tid], fenc(slg));
  }
  __syncthreads();

  if (tid < npg) s_mx[tid] = fdec(s_mxu[tid]);
  if (tid == 0) {
    int run = 0;
    for (int n = 0; n < npg; n++) { s_start[n] = run; run += s_cnt[n]; }
    s_start[npg] = run;
  }
  __syncthreads();

  float ex = 0.f;
  if (tid < EPG && ok) {
    ex = expf(lg - s_mx[dl]);
    atomicAdd(&s_den[dl], ex);
    int p = s_start[dl] + atomicAdd(&s_cur[dl], 1);
    s_list[p] = tid;
  }
  if (tid < npg) {
    float e2 = expf(slg - s_mx[tid]);
    s_self[tid] = e2;
    atomicAdd(&s_den[tid], e2);
  }
  __syncthreads();

  if (tid < EPG && ok) s_alpha[tid] = ex / s_den[dl];
  if (tid < npg) s_self[tid] = s_self[tid] / s_den[tid];
  __syncthreads();

  const int c = h * DD + tid * 4;
  const float4 b4 = *(const float4*)&gbias[c];
  for (int n = 0; n < npg; n++) {
    const size_t rowo = (size_t)(base + n) * HC + c;
    const float4 v = *(const float4*)&xl[rowo];
    float a0 = s_self[n];
    float4 acc;
    acc.x = a0 * v.x; acc.y = a0 * v.y; acc.z = a0 * v.z; acc.w = a0 * v.w;
    const int st = s_start[n], en = s_start[n + 1];
    for (int q = st; q < en; q++) {
      int e = s_list[q];
      float a = s_alpha[e];
      const float4 u = *(const float4*)&xl[(size_t)(base + s_srcl[e]) * HC + c];
      acc.x += a * u.x; acc.y += a * u.y; acc.z += a * u.z; acc.w += a * u.w;
    }
    acc.x += b4.x; acc.y += b4.y; acc.z += b4.z; acc.w += b4.w;
    *(float4*)&out[rowo] = acc;
  }
}

// ---------------- TopK pool ----------------
__global__ __launch_bounds__(256) void pool_kernel(
    const float* __restrict__ hbuf, const float* __restrict__ sc,
    const int* __restrict__ cs, const int* __restrict__ cd, const int* __restrict__ cm,
    int npg, int k,
    float* __restrict__ xnew, float* __restrict__ gap,
    int* __restrict__ ns, int* __restrict__ nd, int* __restrict__ nm)
{
  int g = blockIdx.x, tid = threadIdx.x;
  __shared__ float ssc[32];
  __shared__ int sord[32];
  __shared__ int snp[32];
  if (tid < npg) ssc[tid] = sc[g * npg + tid];
  __syncthreads();
  if (tid == 0) {
    for (int i = 0; i < npg; i++) sord[i] = i;
    for (int i = 1; i < npg; i++) {
      int oi = sord[i]; float v = ssc[oi]; int j = i - 1;
      while (j >= 0 && ssc[sord[j]] < v) { sord[j + 1] = sord[j]; j--; }
      sord[j + 1] = oi;
    }
  }
  __syncthreads();
  if (tid < npg) snp[tid] = -1;
  __syncthreads();
  if (tid < k) snp[sord[tid]] = tid;
  __syncthreads();

  float acc0 = 0.f, acc1 = 0.f, acc2 = 0.f, acc3 = 0.f;
  for (int r = 0; r < k; r++) {
    int ol = sord[r];
    float s = ssc[ol];
    const float* hr = hbuf + (size_t)(g * npg + ol) * DD;
    float* xr = xnew + (size_t)(g * k + r) * DD;
    float v0 = hr[tid] * s, v1 = hr[tid + 256] * s, v2 = hr[tid + 512] * s, v3 = hr[tid + 768] * s;
    xr[tid] = v0; xr[tid + 256] = v1; xr[tid + 512] = v2; xr[tid + 768] = v3;
    acc0 += v0; acc1 += v1; acc2 += v2; acc3 += v3;
  }
  float fk = (float)k;
  gap[(size_t)g * DD + tid]       = acc0 / fk;
  gap[(size_t)g * DD + tid + 256] = acc1 / fk;
  gap[(size_t)g * DD + tid + 512] = acc2 / fk;
  gap[(size_t)g * DD + tid + 768] = acc3 / fk;

  for (int e = tid; e < EPG; e += 256) {
    int ei = g * EPG + e;
    int ok = cm ? cm[ei] : 1;
    int m2 = 0, a = 0, b2 = 0;
    if (ok) {
      int sl = cs[ei] - g * npg, dl = cd[ei] - g * npg;
      int nsl = snp[sl], ndl = snp[dl];
      if (nsl >= 0 && ndl >= 0) { m2 = 1; a = g * k + nsl; b2 = g * k + ndl; }
    }
    ns[ei] = a; nd[ei] = b2; nm[ei] = m2;
  }
}

__global__ __launch_bounds__(256) void zadd_kernel(
    const float* __restrict__ a, const float* __restrict__ b,
    const float* __restrict__ c, float* __restrict__ o)
{
  int i = blockIdx.x * 256 + threadIdx.x;
  o[i] = a[i] + b[i] + c[i];
}

__global__ __launch_bounds__(256) void l2_kernel(
    const float* __restrict__ z2, const float* __restrict__ w,
    const float* __restrict__ b, float* __restrict__ out)
{
  int row = (blockIdx.x * 256 + threadIdx.x) >> 6;
  int lane = threadIdx.x & 63;
  if (row >= 256) return;
  const float* r = z2 + (size_t)row * DD;
  float s = 0.f;
  #pragma unroll 4
  for (int i = lane; i < DD; i += 64) s += r[i] * w[i];
  #pragma unroll
  for (int off = 32; off; off >>= 1) s += __shfl_down(s, off);
  if (lane == 0) out[row] = s + b[0];
}

extern "C" void kernel_launch(void* const* d_in, const int* in_sizes, int n_in,
                              void* d_out, int out_size, void* d_ws, size_t ws_size,
                              hipStream_t stream)
{
  (void)in_sizes; (void)n_in; (void)out_size; (void)ws_size;
  const float* x    = (const float*)d_in[0];
  const int*   eidx = (const int*)d_in[2];
  const float* g1W = (const float*)d_in[4];
  const float* g1as= (const float*)d_in[5];
  const float* g1ad= (const float*)d_in[6];
  const float* g1b = (const float*)d_in[7];
  const float* t1W = (const float*)d_in[8];
  const float* t1b = (const float*)d_in[9];
  const float* p1  = (const float*)d_in[10];
  const float* g2W = (const float*)d_in[11];
  const float* g2as= (const float*)d_in[12];
  const float* g2ad= (const float*)d_in[13];
  const float* g2b = (const float*)d_in[14];
  const float* t2W = (const float*)d_in[15];
  const float* t2b = (const float*)d_in[16];
  const float* p2  = (const float*)d_in[17];
  const float* g3W = (const float*)d_in[18];
  const float* g3as= (const float*)d_in[19];
  const float* g3ad= (const float*)d_in[20];
  const float* g3b = (const float*)d_in[21];
  const float* t3W = (const float*)d_in[22];
  const float* t3b = (const float*)d_in[23];
  const float* p3  = (const float*)d_in[24];
  const float* l1W = (const float*)d_in[25];
  const float* l1b = (const float*)d_in[26];
  const float* l2W = (const float*)d_in[27];
  const float* l2b = (const float*)d_in[28];
  float* outp = (float*)d_out;

  float* W = (float*)d_ws;
  size_t o = 0;
  float* bufA = W + o; o += (size_t)8192 * HC;
  float* bufB = W + o; o += (size_t)8192 * HC;
  float* ALS = W + o; o += 8192 * 3;
  float* ALD = W + o; o += 8192 * 3;
  float* SC  = W + o; o += 8192;
  float* NRM = W + o; o += 4;
  float* X1  = W + o; o += 256 * DD;
  float* X2  = W + o; o += 256 * DD;
  float* X3  = W + o; o += 256 * DD;
  float* ZB  = W + o; o += 256 * DD;
  float* Z2  = W + o; o += 256 * DD;
  int* E0s = (int*)(W + o); o += 40960;
  int* E0d = (int*)(W + o); o += 40960;
  int* E0m = (int*)(W + o); o += 40960;
  int* E1s = (int*)(W + o); o += 40960;
  int* E1d = (int*)(W + o); o += 40960;
  int* E1m = (int*)(W + o); o += 40960;
  _Float16* WTH = (_Float16*)(W + o); o += (3200 * 1024) / 2;   // 3.28M halfs
  _Float16* WTL = (_Float16*)(W + o); o += (3200 * 1024) / 2;

  const int* es1 = eidx;
  const int* ed1 = eidx + 40960;

  norm_kernel<<<3, 256, 0, stream>>>(p1, p2, p3, NRM);

  // -------- stage 1: N=8192, npg=32 -> k=26 --------
  wtrans_kernel<<<dim3(96, 1), dim3(32, 8), 0, stream>>>(g1W, WTH, WTL, 30, HC, 32);
  mfma_gemm<<<dim3(24, 64), 256, 0, stream>>>(x, WTH, WTL, nullptr, bufA, 8192, HC, 30, 32);
  al_kernel<<<6144, 256, 0, stream>>>(bufA, g1as, g1ad, ALS, ALD, 8192);
  gat_agg<<<dim3(256, 3), 256, 0, stream>>>(bufA, ALS, ALD, es1, ed1, nullptr, g1b, bufB, 32);
  wtrans_kernel<<<dim3(32, 96), dim3(32, 8), 0, stream>>>(t1W, WTH, WTL, HC, DD, HC);
  mfma_gemm<<<dim3(8, 64), 256, 0, stream>>>(bufB, WTH, WTL, t1b, bufA, 8192, DD, HC, HC);
  score_kernel<<<2048, 256, 0, stream>>>(bufA, p1, NRM, 0, SC, 8192);
  pool_kernel<<<256, 256, 0, stream>>>(bufA, SC, es1, ed1, nullptr, 32, 26, bufB, X1, E0s, E0d, E0m);

  // -------- stage 2: N=6656, npg=26 -> k=13 --------
  wtrans_kernel<<<dim3(96, 32), dim3(32, 8), 0, stream>>>(g2W, WTH, WTL, DD, HC, DD);
  mfma_gemm<<<dim3(24, 52), 256, 0, stream>>>(bufB, WTH, WTL, nullptr, bufA, 6656, HC, DD, DD);
  al_kernel<<<4992, 256, 0, stream>>>(bufA, g2as, g2ad, ALS, ALD, 6656);
  gat_agg<<<dim3(256, 3), 256, 0, stream>>>(bufA, ALS, ALD, E0s, E0d, E0m, g2b, bufB, 26);
  wtrans_kernel<<<dim3(32, 96), dim3(32, 8), 0, stream>>>(t2W, WTH, WTL, HC, DD, HC);
  mfma_gemm<<<dim3(8, 52), 256, 0, stream>>>(bufB, WTH, WTL, t2b, bufA, 6656, DD, HC, HC);
  score_kernel<<<1664, 256, 0, stream>>>(bufA, p2, NRM, 1, SC, 6656);
  pool_kernel<<<256, 256, 0, stream>>>(bufA, SC, E0s, E0d, E0m, 26, 13, bufB, X2, E1s, E1d, E1m);

  // -------- stage 3: N=3328, npg=13 -> k=4 --------
  wtrans_kernel<<<dim3(96, 32), dim3(32, 8), 0, stream>>>(g3W, WTH, WTL, DD, HC, DD);
  mfma_gemm<<<dim3(24, 26), 256, 0, stream>>>(bufB, WTH, WTL, nullptr, bufA, 3328, HC, DD, DD);
  al_kernel<<<2496, 256, 0, stream>>>(bufA, g3as, g3ad, ALS, ALD, 3328);
  gat_agg<<<dim3(256, 3), 256, 0, stream>>>(bufA, ALS, ALD, E1s, E1d, E1m, g3b, bufB, 13);
  wtrans_kernel<<<dim3(32, 96), dim3(32, 8), 0, stream>>>(t3W, WTH, WTL, HC, DD, HC);
  mfma_gemm<<<dim3(8, 26), 256, 0, stream>>>(bufB, WTH, WTL, t3b, bufA, 3328, DD, HC, HC);
  score_kernel<<<832, 256, 0, stream>>>(bufA, p3, NRM, 2, SC, 3328);
  pool_kernel<<<256, 256, 0, stream>>>(bufA, SC, E1s, E1d, E1m, 13, 4, bufB, X3, E0s, E0d, E0m);

  // -------- head --------
  zadd_kernel<<<1024, 256, 0, stream>>>(X1, X2, X3, ZB);
  sgemm_kernel<<<dim3(8, 2), 256, 0, stream>>>(ZB, l1W, l1b, Z2, 256, DD, DD, 1);
  l2_kernel<<<64, 256, 0, stream>>>(Z2, l2W, l2b, outp);
}